// Round 7
// baseline (372.321 us; speedup 1.0000x reference)
//
#include <hip/hip_runtime.h>

#define NN   50000
#define FIN  256
#define HD   128
#define CC   64
#define KK   4
#define RWSS 16
#define NRW  (NN*RWSS)          // 800000
#define KNRW (KK*NRW)           // 3200000

typedef unsigned int   uint32;
typedef unsigned short ushort_t;

typedef __attribute__((ext_vector_type(8))) short short8v;   // 8 bf16
typedef __attribute__((ext_vector_type(4))) float float4v;   // MFMA acc
typedef __attribute__((ext_vector_type(4))) uint32 uint4v;   // native 16B vec

static __device__ __forceinline__ float bf16lo(uint32 u) {
    return __uint_as_float(u << 16);
}
static __device__ __forceinline__ float bf16hi(uint32 u) {
    return __uint_as_float(u & 0xFFFF0000u);
}
static __device__ __forceinline__ ushort_t f2bf16(float f) {
    uint32 u = __float_as_uint(f);
    uint32 r = u + 0x7FFFu + ((u >> 16) & 1u);   // RNE
    return (ushort_t)(r >> 16);
}

// ---------------------------------------------------------------------------
// One-time weight conversion fp32 -> bf16 k-major 16B chunks [k8][col].
// ---------------------------------------------------------------------------
static __device__ __forceinline__ uint4 packw(const float* p) {
    const float4 w0 = *(const float4*)p;
    const float4 w1 = *(const float4*)(p + 4);
    uint4 q;
    q.x = (uint32)f2bf16(w0.x) | ((uint32)f2bf16(w0.y) << 16);
    q.y = (uint32)f2bf16(w0.z) | ((uint32)f2bf16(w0.w) << 16);
    q.z = (uint32)f2bf16(w1.x) | ((uint32)f2bf16(w1.y) << 16);
    q.w = (uint32)f2bf16(w1.z) | ((uint32)f2bf16(w1.w) << 16);
    return q;
}

__global__ __launch_bounds__(256) void prep_w_kernel(
    const float* __restrict__ w0, const float* __restrict__ w1,
    const float* __restrict__ wo,
    uint4* __restrict__ t0, uint4* __restrict__ t1, uint4* __restrict__ to_)
{
    const int idx = blockIdx.x * 256 + threadIdx.x;
    if (idx < 4096) {                       // lin0: [k8][j], j<128, k8<32
        const int jj = idx & 127, k8 = idx >> 7;
        t0[idx] = packw(w0 + (size_t)jj * FIN + 8 * k8);
    } else if (idx < 6144) {                // lin1: [k8][j], j<128, k8<16
        const int li = idx - 4096;
        const int jj = li & 127, k8 = li >> 7;
        t1[li] = packw(w1 + (size_t)jj * HD + 8 * k8);
    } else if (idx < 7168) {                // lout: [k8][c], c<64, k8<16
        const int li = idx - 6144;
        const int jj = li & 63, k8 = li >> 6;
        to_[li] = packw(wo + (size_t)jj * HD + 8 * k8);
    }
}

// ---------------------------------------------------------------------------
// MFMA linear + fused attention projections. B-fragments straight from the
// bf16 W table. Block = 4 waves; wave owns 16 rows x 128 cols.
// Output h16s is SLICE-MAJOR: [slice s][node][32 ch], s = ch>>5.
// ---------------------------------------------------------------------------
template<int DIN, bool ABF16>
__global__ __launch_bounds__(256) void linear_mfma_kernel(
    const void* __restrict__ Ain, const uint4* __restrict__ W16,
    const float* __restrict__ bias,
    const float* __restrict__ alw, const float* __restrict__ alb,
    const float* __restrict__ arw, const float* __restrict__ arb,
    ushort_t* __restrict__ h16s, float* __restrict__ al, float* __restrict__ ar)
{
    const int tid  = threadIdx.x;
    const int wid  = tid >> 6;
    const int lane = tid & 63;
    const int mrow = lane & 15;
    const int kq   = lane >> 4;
    const int row  = blockIdx.x * 64 + wid * 16 + mrow;
    const int arow = row < NN ? row : NN - 1;

    float4v acc[8];
#pragma unroll
    for (int t = 0; t < 8; ++t) acc[t] = (float4v){0.f, 0.f, 0.f, 0.f};

    for (int f0 = 0; f0 < DIN; f0 += 32) {
        short8v a;
        if constexpr (ABF16) {
            a = *(const short8v*)((const ushort_t*)Ain + (size_t)arow * DIN + f0 + 8 * kq);
        } else {
            const float* ap = (const float*)Ain + (size_t)arow * DIN + f0 + 8 * kq;
            const float4 a0 = *(const float4*)ap;
            const float4 a1 = *(const float4*)(ap + 4);
            a[0] = (short)f2bf16(a0.x); a[1] = (short)f2bf16(a0.y);
            a[2] = (short)f2bf16(a0.z); a[3] = (short)f2bf16(a0.w);
            a[4] = (short)f2bf16(a1.x); a[5] = (short)f2bf16(a1.y);
            a[6] = (short)f2bf16(a1.z); a[7] = (short)f2bf16(a1.w);
        }
        const int k8 = (f0 >> 3) + kq;
#pragma unroll
        for (int t = 0; t < 8; ++t) {
            const short8v b = ((const short8v*)W16)[(k8 << 7) + 16 * t + mrow];
            acc[t] = __builtin_amdgcn_mfma_f32_16x16x32_bf16(a, b, acc[t], 0, 0, 0);
        }
    }

    // ---- epilogue: bias, slice-major bf16 store, fused al/ar ----
    float pa[4] = {0.f, 0.f, 0.f, 0.f};
    float pr[4] = {0.f, 0.f, 0.f, 0.f};
    float hb[8][4];
#pragma unroll
    for (int t = 0; t < 8; ++t) {
        const float bj = bias[16 * t + mrow];
        const float wl = alw[16 * t + mrow];
        const float wr = arw[16 * t + mrow];
#pragma unroll
        for (int g = 0; g < 4; ++g) {
            const float h = acc[t][g] + bj;
            hb[t][g] = h;
            pa[g] = fmaf(h, wl, pa[g]);
            pr[g] = fmaf(h, wr, pr[g]);
        }
    }
    const int rbase = blockIdx.x * 64 + wid * 16 + 4 * kq;
#pragma unroll
    for (int g = 0; g < 4; ++g) {
        const int orow = rbase + g;
        if (orow < NN) {
#pragma unroll
            for (int t = 0; t < 8; ++t) {
                // channel c = 16t + mrow; slice = t>>1; offset = 16*(t&1)+mrow
                h16s[(size_t)(t >> 1) * (NN * 32) + (size_t)orow * 32 +
                     16 * (t & 1) + mrow] = f2bf16(hb[t][g]);
            }
        }
    }
#pragma unroll
    for (int o = 8; o >= 1; o >>= 1) {
#pragma unroll
        for (int g = 0; g < 4; ++g) {
            pa[g] += __shfl_xor(pa[g], o, 16);
            pr[g] += __shfl_xor(pr[g], o, 16);
        }
    }
    if (mrow == 0) {
#pragma unroll
        for (int g = 0; g < 4; ++g) {
            const int orow = rbase + g;
            if (orow < NN) {
                al[orow] = pa[g] + alb[0];
                ar[orow] = pr[g] + arb[0];
            }
        }
    }
}

// ---------------------------------------------------------------------------
// Pair prep: packed (w_bf16 << 16 | e) per (node, k, j). One wave per node.
// ---------------------------------------------------------------------------
__global__ __launch_bounds__(256) void prep_pairs_kernel(
    const int* __restrict__ ends_l, const float* __restrict__ al,
    const float* __restrict__ ar, const float* __restrict__ att_l,
    uint32* __restrict__ pw)
{
    const int wv   = threadIdx.x >> 6;
    const int lane = threadIdx.x & 63;
    const int node = blockIdx.x * 4 + wv;
    const int k    = lane >> 4;
    const int j    = lane & 15;

    const int e = __builtin_nontemporal_load(ends_l + (size_t)k * NRW + node * RWSS + j);
    float lg = al[node] + ar[e];
    lg = (lg > 0.f) ? lg : 0.2f * lg;
    float m = lg;
#pragma unroll
    for (int o = 8; o >= 1; o >>= 1) m = fmaxf(m, __shfl_xor(m, o, 16));
    const float ex = __expf(lg - m);
    float s = ex;
#pragma unroll
    for (int o = 8; o >= 1; o >>= 1) s += __shfl_xor(s, o, 16);
    const float w = ex / s * att_l[k + 1] * (1.0f / RWSS);
    const uint32 packed = ((uint32)f2bf16(w) << 16) | (uint32)e;   // e < 65536
    __builtin_nontemporal_store(packed, pw + (size_t)node * 64 + lane);
}

// ---------------------------------------------------------------------------
// Slice aggregation: ONE SLICE PER DISPATCH (s is a kernel arg; 4 sequential
// dispatches per layer give hard temporal separation -> slice table stays
// L2-resident). Block = 256 thr = 4 waves = 16 nodes; wave handles 4 nodes
// (16 lanes each): lane = g*16 + r*4 + q. Per iteration each lane gathers
// dwordx4 (8 ch) of row j = 4i+r of its node; 16 iters for 64 samples.
// Pairs staged in LDS (NT load; stride 68 conflict-free). NT output store.
// ---------------------------------------------------------------------------
__global__ __launch_bounds__(256, 8) void aggr_slice_kernel(
    const ushort_t* __restrict__ h16s, const uint32* __restrict__ pw,
    const float* __restrict__ att_l, ushort_t* __restrict__ agg16, int s)
{
    __shared__ uint32 pair_s[16 * 68];
    const int tid   = threadIdx.x;
    const int node0 = blockIdx.x * 16;
    const char* hbase = (const char*)(h16s + (size_t)s * (NN * 32));

    // stage pairs: 16 nodes x 64 pairs (one uint4v per thread, NT)
    {
        const uint4v p4 = __builtin_nontemporal_load(
            (const uint4v*)(pw + (size_t)node0 * 64) + tid);
        const int nl = tid >> 4;
        const int j4 = (tid & 15) << 2;
        *(uint4v*)&pair_s[nl * 68 + j4] = p4;
    }
    __syncthreads();

    const int lane = tid & 63;
    const int w    = tid >> 6;
    const int g    = lane >> 4;
    const int r    = (lane >> 2) & 3;
    const int q    = lane & 3;
    const int nl   = w * 4 + g;
    const uint32 qb = (uint32)(q << 4);          // chunk byte offset

    const uint32* ps = &pair_s[nl * 68 + r];

    float acc[8];
#pragma unroll
    for (int c = 0; c < 8; ++c) acc[c] = 0.f;

#pragma unroll
    for (int i = 0; i < 16; ++i) {
        const uint32 p   = ps[4 * i];
        const uint32 off = ((p & 0xFFFFu) << 6) + qb;
        const uint4v v   = *(const uint4v*)(hbase + off);
        const float  wgt = __uint_as_float(p & 0xFFFF0000u);
        acc[0] = fmaf(bf16lo(v.x), wgt, acc[0]);
        acc[1] = fmaf(bf16hi(v.x), wgt, acc[1]);
        acc[2] = fmaf(bf16lo(v.y), wgt, acc[2]);
        acc[3] = fmaf(bf16hi(v.y), wgt, acc[3]);
        acc[4] = fmaf(bf16lo(v.z), wgt, acc[4]);
        acc[5] = fmaf(bf16hi(v.z), wgt, acc[5]);
        acc[6] = fmaf(bf16lo(v.w), wgt, acc[6]);
        acc[7] = fmaf(bf16hi(v.w), wgt, acc[7]);
    }

#pragma unroll
    for (int c = 0; c < 8; ++c) {
        acc[c] += __shfl_xor(acc[c], 4, 16);
        acc[c] += __shfl_xor(acc[c], 8, 16);
    }

    if (r == 0) {
        const int node = node0 + nl;
        const uint4v v = *(const uint4v*)(hbase + (((uint32)node << 6) + qb));
        const float a0 = att_l[0];
        acc[0] = fmaf(bf16lo(v.x), a0, acc[0]);
        acc[1] = fmaf(bf16hi(v.x), a0, acc[1]);
        acc[2] = fmaf(bf16lo(v.y), a0, acc[2]);
        acc[3] = fmaf(bf16hi(v.y), a0, acc[3]);
        acc[4] = fmaf(bf16lo(v.z), a0, acc[4]);
        acc[5] = fmaf(bf16hi(v.z), a0, acc[5]);
        acc[6] = fmaf(bf16lo(v.w), a0, acc[6]);
        acc[7] = fmaf(bf16hi(v.w), a0, acc[7]);
        uint4v o;
        o.x = (uint32)f2bf16(acc[0]) | ((uint32)f2bf16(acc[1]) << 16);
        o.y = (uint32)f2bf16(acc[2]) | ((uint32)f2bf16(acc[3]) << 16);
        o.z = (uint32)f2bf16(acc[4]) | ((uint32)f2bf16(acc[5]) << 16);
        o.w = (uint32)f2bf16(acc[6]) | ((uint32)f2bf16(acc[7]) << 16);
        __builtin_nontemporal_store(
            o, (uint4v*)((char*)agg16 + (size_t)node * 256 + s * 64 + qb));
    }
}

// ---------------------------------------------------------------------------
// Output head: MFMA GEMM (h @ lout_w^T + b) + fused log_softmax.
// ---------------------------------------------------------------------------
__global__ __launch_bounds__(256) void out_mfma_kernel(
    const ushort_t* __restrict__ agg16, const uint4* __restrict__ WO16,
    const float* __restrict__ lb, float* __restrict__ outp)
{
    const int tid  = threadIdx.x;
    const int wid  = tid >> 6;
    const int lane = tid & 63;
    const int mrow = lane & 15;
    const int kq   = lane >> 4;
    const int row  = blockIdx.x * 64 + wid * 16 + mrow;
    const int arow = row < NN ? row : NN - 1;

    float4v acc[4];
#pragma unroll
    for (int t = 0; t < 4; ++t) acc[t] = (float4v){0.f, 0.f, 0.f, 0.f};

#pragma unroll
    for (int f0 = 0; f0 < HD; f0 += 32) {
        const short8v a = *(const short8v*)(agg16 + (size_t)arow * HD + f0 + 8 * kq);
        const int k8 = (f0 >> 3) + kq;
#pragma unroll
        for (int t = 0; t < 4; ++t) {
            const short8v b = ((const short8v*)WO16)[(k8 << 6) + 16 * t + mrow];
            acc[t] = __builtin_amdgcn_mfma_f32_16x16x32_bf16(a, b, acc[t], 0, 0, 0);
        }
    }

    float v[4][4];
    float mx[4] = {-1e30f, -1e30f, -1e30f, -1e30f};
#pragma unroll
    for (int t = 0; t < 4; ++t) {
        const float bj = lb[16 * t + mrow];
#pragma unroll
        for (int g = 0; g < 4; ++g) {
            v[t][g] = acc[t][g] + bj;
            mx[g] = fmaxf(mx[g], v[t][g]);
        }
    }
#pragma unroll
    for (int o = 8; o >= 1; o >>= 1)
#pragma unroll
        for (int g = 0; g < 4; ++g) mx[g] = fmaxf(mx[g], __shfl_xor(mx[g], o, 16));
    float sm[4] = {0.f, 0.f, 0.f, 0.f};
#pragma unroll
    for (int t = 0; t < 4; ++t)
#pragma unroll
        for (int g = 0; g < 4; ++g) sm[g] += __expf(v[t][g] - mx[g]);
#pragma unroll
    for (int o = 8; o >= 1; o >>= 1)
#pragma unroll
        for (int g = 0; g < 4; ++g) sm[g] += __shfl_xor(sm[g], o, 16);
    float lgs[4];
#pragma unroll
    for (int g = 0; g < 4; ++g) lgs[g] = __logf(sm[g]);

    const int rbase = blockIdx.x * 64 + wid * 16 + 4 * kq;
#pragma unroll
    for (int g = 0; g < 4; ++g) {
        const int orow = rbase + g;
        if (orow < NN) {
#pragma unroll
            for (int t = 0; t < 4; ++t)
                outp[(size_t)orow * CC + 16 * t + mrow] = v[t][g] - mx[g] - lgs[g];
        }
    }
}

// ---------------------------------------------------------------------------
extern "C" void kernel_launch(void* const* d_in, const int* in_sizes, int n_in,
                              void* d_out, int out_size, void* d_ws, size_t ws_size,
                              hipStream_t stream)
{
    const float* x      = (const float*)d_in[0];
    const int*   ends   = (const int*)  d_in[1];
    const float* lin0_w = (const float*)d_in[2];
    const float* lin0_b = (const float*)d_in[3];
    const float* lin1_w = (const float*)d_in[4];
    const float* lin1_b = (const float*)d_in[5];
    const float* lout_w = (const float*)d_in[6];
    const float* lout_b = (const float*)d_in[7];
    const float* attl_w = (const float*)d_in[8];
    const float* attl_b = (const float*)d_in[9];
    const float* attr_w = (const float*)d_in[10];
    const float* attr_b = (const float*)d_in[11];
    const float* att    = (const float*)d_in[12];
    float* outp = (float*)d_out;

    // workspace layout (~39 MB)
    ushort_t* h16s  = (ushort_t*)d_ws;                    // slice-major table, 12.8MB
    ushort_t* agg16 = h16s + (size_t)NN * HD;             // row-major agg, 12.8MB
    float*    albuf = (float*)(agg16 + (size_t)NN * HD);  // 50000
    float*    arbuf = albuf + NN;                         // 50000
    uint32*   pw    = (uint32*)(arbuf + NN);              // 3.2M packed pairs, 12.8MB
    uint4*    t0    = (uint4*)(pw + (size_t)KNRW);        // 4096 chunks
    uint4*    t1    = t0 + 4096;                          // 2048 chunks
    uint4*    to_   = t1 + 2048;                          // 1024 chunks

    const int lin_grid = (NN + 63) / 64;   // 782
    const int nb4      = NN / 4;           // 12500, exact
    const int nb16     = NN / 16;          // 3125, exact

    prep_w_kernel<<<28, 256, 0, stream>>>(lin0_w, lin1_w, lout_w, t0, t1, to_);

    // ---- layer 0 ----
    linear_mfma_kernel<FIN, false><<<lin_grid, 256, 0, stream>>>(
        x, t0, lin0_b, attl_w, attl_b, attr_w, attr_b, h16s, albuf, arbuf);
    prep_pairs_kernel<<<nb4, 256, 0, stream>>>(ends, albuf, arbuf, att, pw);
    for (int s = 0; s < 4; ++s)
        aggr_slice_kernel<<<nb16, 256, 0, stream>>>(h16s, pw, att, agg16, s);

    // ---- layer 1 ----
    linear_mfma_kernel<HD, true><<<lin_grid, 256, 0, stream>>>(
        agg16, t1, lin1_b, attl_w + HD, attl_b + 1, attr_w + HD, attr_b + 1,
        h16s, albuf, arbuf);
    prep_pairs_kernel<<<nb4, 256, 0, stream>>>(ends + KNRW, albuf, arbuf,
                                               att + (KK + 1), pw);
    for (int s = 0; s < 4; ++s)
        aggr_slice_kernel<<<nb16, 256, 0, stream>>>(h16s, pw, att + (KK + 1),
                                                    agg16, s);

    // ---- output head ----
    out_mfma_kernel<<<lin_grid, 256, 0, stream>>>(agg16, to_, lout_b, outp);
}

// Round 8
// 226.360 us; speedup vs baseline: 1.6448x; 1.6448x over previous
//
#include <hip/hip_runtime.h>

#define NN   50000
#define FIN  256
#define HD   128
#define CC   64
#define KK   4
#define RWSS 16
#define NRW  (NN*RWSS)          // 800000
#define KNRW (KK*NRW)           // 3200000

typedef unsigned int   uint32;
typedef unsigned short ushort_t;

typedef __attribute__((ext_vector_type(8))) short short8v;   // 8 bf16
typedef __attribute__((ext_vector_type(4))) float float4v;   // MFMA acc
typedef __attribute__((ext_vector_type(4))) uint32 uint4v;   // native 16B vec

static __device__ __forceinline__ float bf16lo(uint32 u) {
    return __uint_as_float(u << 16);
}
static __device__ __forceinline__ float bf16hi(uint32 u) {
    return __uint_as_float(u & 0xFFFF0000u);
}
static __device__ __forceinline__ ushort_t f2bf16(float f) {
    uint32 u = __float_as_uint(f);
    uint32 r = u + 0x7FFFu + ((u >> 16) & 1u);   // RNE
    return (ushort_t)(r >> 16);
}

// ---------------------------------------------------------------------------
// One-time weight conversion fp32 -> bf16 k-major 16B chunks [k8][col].
// ---------------------------------------------------------------------------
static __device__ __forceinline__ uint4 packw(const float* p) {
    const float4 w0 = *(const float4*)p;
    const float4 w1 = *(const float4*)(p + 4);
    uint4 q;
    q.x = (uint32)f2bf16(w0.x) | ((uint32)f2bf16(w0.y) << 16);
    q.y = (uint32)f2bf16(w0.z) | ((uint32)f2bf16(w0.w) << 16);
    q.z = (uint32)f2bf16(w1.x) | ((uint32)f2bf16(w1.y) << 16);
    q.w = (uint32)f2bf16(w1.z) | ((uint32)f2bf16(w1.w) << 16);
    return q;
}

__global__ __launch_bounds__(256) void prep_w_kernel(
    const float* __restrict__ w0, const float* __restrict__ w1,
    const float* __restrict__ wo,
    uint4* __restrict__ t0, uint4* __restrict__ t1, uint4* __restrict__ to_)
{
    const int idx = blockIdx.x * 256 + threadIdx.x;
    if (idx < 4096) {                       // lin0: [k8][j], j<128, k8<32
        const int jj = idx & 127, k8 = idx >> 7;
        t0[idx] = packw(w0 + (size_t)jj * FIN + 8 * k8);
    } else if (idx < 6144) {                // lin1: [k8][j], j<128, k8<16
        const int li = idx - 4096;
        const int jj = li & 127, k8 = li >> 7;
        t1[li] = packw(w1 + (size_t)jj * HD + 8 * k8);
    } else if (idx < 7168) {                // lout: [k8][c], c<64, k8<16
        const int li = idx - 6144;
        const int jj = li & 63, k8 = li >> 6;
        to_[li] = packw(wo + (size_t)jj * HD + 8 * k8);
    }
}

// ---------------------------------------------------------------------------
// MFMA linear + fused attention projections. B-fragments straight from the
// bf16 W table. Block = 4 waves; wave owns 16 rows x 128 cols.
// Output h16s is SLICE-MAJOR: [slice s][node][32 ch], s = ch>>5.
// ---------------------------------------------------------------------------
template<int DIN, bool ABF16>
__global__ __launch_bounds__(256) void linear_mfma_kernel(
    const void* __restrict__ Ain, const uint4* __restrict__ W16,
    const float* __restrict__ bias,
    const float* __restrict__ alw, const float* __restrict__ alb,
    const float* __restrict__ arw, const float* __restrict__ arb,
    ushort_t* __restrict__ h16s, float* __restrict__ al, float* __restrict__ ar)
{
    const int tid  = threadIdx.x;
    const int wid  = tid >> 6;
    const int lane = tid & 63;
    const int mrow = lane & 15;
    const int kq   = lane >> 4;
    const int row  = blockIdx.x * 64 + wid * 16 + mrow;
    const int arow = row < NN ? row : NN - 1;

    float4v acc[8];
#pragma unroll
    for (int t = 0; t < 8; ++t) acc[t] = (float4v){0.f, 0.f, 0.f, 0.f};

    for (int f0 = 0; f0 < DIN; f0 += 32) {
        short8v a;
        if constexpr (ABF16) {
            a = *(const short8v*)((const ushort_t*)Ain + (size_t)arow * DIN + f0 + 8 * kq);
        } else {
            const float* ap = (const float*)Ain + (size_t)arow * DIN + f0 + 8 * kq;
            const float4 a0 = *(const float4*)ap;
            const float4 a1 = *(const float4*)(ap + 4);
            a[0] = (short)f2bf16(a0.x); a[1] = (short)f2bf16(a0.y);
            a[2] = (short)f2bf16(a0.z); a[3] = (short)f2bf16(a0.w);
            a[4] = (short)f2bf16(a1.x); a[5] = (short)f2bf16(a1.y);
            a[6] = (short)f2bf16(a1.z); a[7] = (short)f2bf16(a1.w);
        }
        const int k8 = (f0 >> 3) + kq;
#pragma unroll
        for (int t = 0; t < 8; ++t) {
            const short8v b = ((const short8v*)W16)[(k8 << 7) + 16 * t + mrow];
            acc[t] = __builtin_amdgcn_mfma_f32_16x16x32_bf16(a, b, acc[t], 0, 0, 0);
        }
    }

    // ---- epilogue: bias, slice-major bf16 store, fused al/ar ----
    float pa[4] = {0.f, 0.f, 0.f, 0.f};
    float pr[4] = {0.f, 0.f, 0.f, 0.f};
    float hb[8][4];
#pragma unroll
    for (int t = 0; t < 8; ++t) {
        const float bj = bias[16 * t + mrow];
        const float wl = alw[16 * t + mrow];
        const float wr = arw[16 * t + mrow];
#pragma unroll
        for (int g = 0; g < 4; ++g) {
            const float h = acc[t][g] + bj;
            hb[t][g] = h;
            pa[g] = fmaf(h, wl, pa[g]);
            pr[g] = fmaf(h, wr, pr[g]);
        }
    }
    const int rbase = blockIdx.x * 64 + wid * 16 + 4 * kq;
#pragma unroll
    for (int g = 0; g < 4; ++g) {
        const int orow = rbase + g;
        if (orow < NN) {
#pragma unroll
            for (int t = 0; t < 8; ++t) {
                // channel c = 16t + mrow; slice = t>>1; offset = 16*(t&1)+mrow
                h16s[(size_t)(t >> 1) * (NN * 32) + (size_t)orow * 32 +
                     16 * (t & 1) + mrow] = f2bf16(hb[t][g]);
            }
        }
    }
#pragma unroll
    for (int o = 8; o >= 1; o >>= 1) {
#pragma unroll
        for (int g = 0; g < 4; ++g) {
            pa[g] += __shfl_xor(pa[g], o, 16);
            pr[g] += __shfl_xor(pr[g], o, 16);
        }
    }
    if (mrow == 0) {
#pragma unroll
        for (int g = 0; g < 4; ++g) {
            const int orow = rbase + g;
            if (orow < NN) {
                al[orow] = pa[g] + alb[0];
                ar[orow] = pr[g] + arb[0];
            }
        }
    }
}

// ---------------------------------------------------------------------------
// Pair prep: packed (w_bf16 << 16 | e) per (node, k, j). One wave per node.
// ---------------------------------------------------------------------------
__global__ __launch_bounds__(256) void prep_pairs_kernel(
    const int* __restrict__ ends_l, const float* __restrict__ al,
    const float* __restrict__ ar, const float* __restrict__ att_l,
    uint32* __restrict__ pw)
{
    const int wv   = threadIdx.x >> 6;
    const int lane = threadIdx.x & 63;
    const int node = blockIdx.x * 4 + wv;
    const int k    = lane >> 4;
    const int j    = lane & 15;

    const int e = __builtin_nontemporal_load(ends_l + (size_t)k * NRW + node * RWSS + j);
    float lg = al[node] + ar[e];
    lg = (lg > 0.f) ? lg : 0.2f * lg;
    float m = lg;
#pragma unroll
    for (int o = 8; o >= 1; o >>= 1) m = fmaxf(m, __shfl_xor(m, o, 16));
    const float ex = __expf(lg - m);
    float s = ex;
#pragma unroll
    for (int o = 8; o >= 1; o >>= 1) s += __shfl_xor(s, o, 16);
    const float w = ex / s * att_l[k + 1] * (1.0f / RWSS);
    const uint32 packed = ((uint32)f2bf16(w) << 16) | (uint32)e;   // e < 65536
    __builtin_nontemporal_store(packed, pw + (size_t)node * 64 + lane);
}

// ---------------------------------------------------------------------------
// Aggregation v3: ONE dispatch per layer; slice pinned to an XCD pair via
// bid&7 (round-robin block->XCD): each XCD's private L2 permanently holds one
// 3.2 MB channel-slice of the table. Block = 256 = 4 waves = 16 nodes.
// Wave = 4 nodes; lane = g*16 + r*4 + q (g=node, r=row-slot, q=16B chunk).
// 16 unrolled iters: pair via immediate-offset ds_read (stride-68 LDS rows,
// conflict-free), gather dwordx4 (8 ch), 8 fma. Reduce = 2 shfl_xor over r.
// ---------------------------------------------------------------------------
__global__ __launch_bounds__(256, 4) void aggr_slice_kernel(
    const ushort_t* __restrict__ h16s, const uint32* __restrict__ pw,
    const float* __restrict__ att_l, ushort_t* __restrict__ agg16)
{
    const int bid = blockIdx.x;
    const int xcd = bid & 7;
    const int s   = xcd >> 1;                       // slice 0..3
    const int ng  = (bid >> 3) + (xcd & 1) * 1563;  // node-group within slice
    if (ng >= 3125) return;                         // block-uniform guard
    const int node0 = ng * 16;

    __shared__ uint32 pair_s[16 * 68];
    const int tid = threadIdx.x;
    // stage 1024 pairs (16 nodes x 64), NT dwordx4, stride-68 LDS rows
    {
        const uint4v p4 = __builtin_nontemporal_load(
            (const uint4v*)(pw + (size_t)node0 * 64) + tid);
        const int nl = tid >> 4;
        const int sm = (4 * tid) & 63;
        *(uint4v*)&pair_s[nl * 68 + sm] = p4;
    }
    __syncthreads();

    const int lane = tid & 63;
    const int w    = tid >> 6;
    const int g    = lane >> 4;
    const int r    = (lane >> 2) & 3;
    const int q    = lane & 3;
    const int nl   = w * 4 + g;
    const uint32 qb = (uint32)(q << 4);
    const char* hbase = (const char*)(h16s + (size_t)s * (NN * 32));
    const uint32* ps = &pair_s[nl * 68 + r];

    float acc[8];
#pragma unroll
    for (int c = 0; c < 8; ++c) acc[c] = 0.f;

#pragma unroll
    for (int i = 0; i < 16; ++i) {
        const uint32 p   = ps[4 * i];                 // imm-offset ds_read
        const uint32 off = ((p & 0xFFFFu) << 6) + qb;
        const uint4v v   = *(const uint4v*)(hbase + off);
        const float  wgt = __uint_as_float(p & 0xFFFF0000u);
        acc[0] = fmaf(bf16lo(v.x), wgt, acc[0]);
        acc[1] = fmaf(bf16hi(v.x), wgt, acc[1]);
        acc[2] = fmaf(bf16lo(v.y), wgt, acc[2]);
        acc[3] = fmaf(bf16hi(v.y), wgt, acc[3]);
        acc[4] = fmaf(bf16lo(v.z), wgt, acc[4]);
        acc[5] = fmaf(bf16hi(v.z), wgt, acc[5]);
        acc[6] = fmaf(bf16lo(v.w), wgt, acc[6]);
        acc[7] = fmaf(bf16hi(v.w), wgt, acc[7]);
    }

#pragma unroll
    for (int c = 0; c < 8; ++c) {
        acc[c] += __shfl_xor(acc[c], 4, 16);
        acc[c] += __shfl_xor(acc[c], 8, 16);
    }

    if (r == 0) {
        const int node = node0 + nl;
        const uint4v v = *(const uint4v*)(hbase + (((uint32)node << 6) + qb));
        const float a0 = att_l[0];
        acc[0] = fmaf(bf16lo(v.x), a0, acc[0]);
        acc[1] = fmaf(bf16hi(v.x), a0, acc[1]);
        acc[2] = fmaf(bf16lo(v.y), a0, acc[2]);
        acc[3] = fmaf(bf16hi(v.y), a0, acc[3]);
        acc[4] = fmaf(bf16lo(v.z), a0, acc[4]);
        acc[5] = fmaf(bf16hi(v.z), a0, acc[5]);
        acc[6] = fmaf(bf16lo(v.w), a0, acc[6]);
        acc[7] = fmaf(bf16hi(v.w), a0, acc[7]);
        uint4v o;
        o.x = (uint32)f2bf16(acc[0]) | ((uint32)f2bf16(acc[1]) << 16);
        o.y = (uint32)f2bf16(acc[2]) | ((uint32)f2bf16(acc[3]) << 16);
        o.z = (uint32)f2bf16(acc[4]) | ((uint32)f2bf16(acc[5]) << 16);
        o.w = (uint32)f2bf16(acc[6]) | ((uint32)f2bf16(acc[7]) << 16);
        __builtin_nontemporal_store(
            o, (uint4v*)((char*)agg16 + (size_t)node * 256 + s * 64 + qb));
    }
}

// ---------------------------------------------------------------------------
// Output head: MFMA GEMM (h @ lout_w^T + b) + fused log_softmax.
// ---------------------------------------------------------------------------
__global__ __launch_bounds__(256) void out_mfma_kernel(
    const ushort_t* __restrict__ agg16, const uint4* __restrict__ WO16,
    const float* __restrict__ lb, float* __restrict__ outp)
{
    const int tid  = threadIdx.x;
    const int wid  = tid >> 6;
    const int lane = tid & 63;
    const int mrow = lane & 15;
    const int kq   = lane >> 4;
    const int row  = blockIdx.x * 64 + wid * 16 + mrow;
    const int arow = row < NN ? row : NN - 1;

    float4v acc[4];
#pragma unroll
    for (int t = 0; t < 4; ++t) acc[t] = (float4v){0.f, 0.f, 0.f, 0.f};

#pragma unroll
    for (int f0 = 0; f0 < HD; f0 += 32) {
        const short8v a = *(const short8v*)(agg16 + (size_t)arow * HD + f0 + 8 * kq);
        const int k8 = (f0 >> 3) + kq;
#pragma unroll
        for (int t = 0; t < 4; ++t) {
            const short8v b = ((const short8v*)WO16)[(k8 << 6) + 16 * t + mrow];
            acc[t] = __builtin_amdgcn_mfma_f32_16x16x32_bf16(a, b, acc[t], 0, 0, 0);
        }
    }

    float v[4][4];
    float mx[4] = {-1e30f, -1e30f, -1e30f, -1e30f};
#pragma unroll
    for (int t = 0; t < 4; ++t) {
        const float bj = lb[16 * t + mrow];
#pragma unroll
        for (int g = 0; g < 4; ++g) {
            v[t][g] = acc[t][g] + bj;
            mx[g] = fmaxf(mx[g], v[t][g]);
        }
    }
#pragma unroll
    for (int o = 8; o >= 1; o >>= 1)
#pragma unroll
        for (int g = 0; g < 4; ++g) mx[g] = fmaxf(mx[g], __shfl_xor(mx[g], o, 16));
    float sm[4] = {0.f, 0.f, 0.f, 0.f};
#pragma unroll
    for (int t = 0; t < 4; ++t)
#pragma unroll
        for (int g = 0; g < 4; ++g) sm[g] += __expf(v[t][g] - mx[g]);
#pragma unroll
    for (int o = 8; o >= 1; o >>= 1)
#pragma unroll
        for (int g = 0; g < 4; ++g) sm[g] += __shfl_xor(sm[g], o, 16);
    float lgs[4];
#pragma unroll
    for (int g = 0; g < 4; ++g) lgs[g] = __logf(sm[g]);

    const int rbase = blockIdx.x * 64 + wid * 16 + 4 * kq;
#pragma unroll
    for (int g = 0; g < 4; ++g) {
        const int orow = rbase + g;
        if (orow < NN) {
#pragma unroll
            for (int t = 0; t < 4; ++t)
                outp[(size_t)orow * CC + 16 * t + mrow] = v[t][g] - mx[g] - lgs[g];
        }
    }
}

// ---------------------------------------------------------------------------
extern "C" void kernel_launch(void* const* d_in, const int* in_sizes, int n_in,
                              void* d_out, int out_size, void* d_ws, size_t ws_size,
                              hipStream_t stream)
{
    const float* x      = (const float*)d_in[0];
    const int*   ends   = (const int*)  d_in[1];
    const float* lin0_w = (const float*)d_in[2];
    const float* lin0_b = (const float*)d_in[3];
    const float* lin1_w = (const float*)d_in[4];
    const float* lin1_b = (const float*)d_in[5];
    const float* lout_w = (const float*)d_in[6];
    const float* lout_b = (const float*)d_in[7];
    const float* attl_w = (const float*)d_in[8];
    const float* attl_b = (const float*)d_in[9];
    const float* attr_w = (const float*)d_in[10];
    const float* attr_b = (const float*)d_in[11];
    const float* att    = (const float*)d_in[12];
    float* outp = (float*)d_out;

    // workspace layout (~39 MB)
    ushort_t* h16s  = (ushort_t*)d_ws;                    // slice-major table, 12.8MB
    ushort_t* agg16 = h16s + (size_t)NN * HD;             // row-major agg, 12.8MB
    float*    albuf = (float*)(agg16 + (size_t)NN * HD);  // 50000
    float*    arbuf = albuf + NN;                         // 50000
    uint32*   pw    = (uint32*)(arbuf + NN);              // 3.2M packed pairs, 12.8MB
    uint4*    t0    = (uint4*)(pw + (size_t)KNRW);        // 4096 chunks
    uint4*    t1    = t0 + 4096;                          // 2048 chunks
    uint4*    to_   = t1 + 2048;                          // 1024 chunks

    const int lin_grid  = (NN + 63) / 64;   // 782
    const int nb4       = NN / 4;           // 12500, exact
    const int aggr_grid = 8 * 1563;         // 12504 (xcd-pinned slices)

    prep_w_kernel<<<28, 256, 0, stream>>>(lin0_w, lin1_w, lout_w, t0, t1, to_);

    // ---- layer 0 ----
    linear_mfma_kernel<FIN, false><<<lin_grid, 256, 0, stream>>>(
        x, t0, lin0_b, attl_w, attl_b, attr_w, attr_b, h16s, albuf, arbuf);
    prep_pairs_kernel<<<nb4, 256, 0, stream>>>(ends, albuf, arbuf, att, pw);
    aggr_slice_kernel<<<aggr_grid, 256, 0, stream>>>(h16s, pw, att, agg16);

    // ---- layer 1 ----
    linear_mfma_kernel<HD, true><<<lin_grid, 256, 0, stream>>>(
        agg16, t1, lin1_b, attl_w + HD, attl_b + 1, attr_w + HD, attr_b + 1,
        h16s, albuf, arbuf);
    prep_pairs_kernel<<<nb4, 256, 0, stream>>>(ends + KNRW, albuf, arbuf,
                                               att + (KK + 1), pw);
    aggr_slice_kernel<<<aggr_grid, 256, 0, stream>>>(h16s, pw, att + (KK + 1), agg16);

    // ---- output head ----
    out_mfma_kernel<<<lin_grid, 256, 0, stream>>>(agg16, to_, lout_b, outp);
}